// Round 1
// baseline (11.271 us; speedup 1.0000x reference)
//
#include <hip/hip_runtime.h>

// CTPN loss: cls CE (pos+neg) + vertical SmoothL1 + side SmoothL1, scalar out.
// Shapes: score/vertical_pred [1,20,512,1024] f32, side_pred [1,10,512,1024] f32.
#define NP 8192
#define NN 8192
#define NV 8192
#define NS 4096
#define NTOT (NP + NN + NV + NS)   // 28672
#define WDIM 1024
#define HW (512 * 1024)
#define NBLK (NTOT / 256)          // 112

__device__ __forceinline__ float smooth_l1(float d) {
    float ad = fabsf(d);
    return ad < 1.0f ? 0.5f * d * d : ad - 0.5f;
}

__global__ __launch_bounds__(256) void ctpn_partial_kernel(
    const float* __restrict__ score,
    const float* __restrict__ vpred,
    const float* __restrict__ spred,
    const int* __restrict__ pos_j, const int* __restrict__ pos_i, const int* __restrict__ pos_k,
    const int* __restrict__ neg_j, const int* __restrict__ neg_i, const int* __restrict__ neg_k,
    const int* __restrict__ vr_j,  const int* __restrict__ vr_i,  const int* __restrict__ vr_k,
    const float* __restrict__ vr_tgt,
    const int* __restrict__ sr_j,  const int* __restrict__ sr_i,  const int* __restrict__ sr_k,
    const float* __restrict__ sr_tgt,
    float* __restrict__ partial)
{
    const int gid = blockIdx.x * 256 + threadIdx.x;
    float v = 0.0f;

    if (gid < NP) {
        // positive classification sample: CE vs class 1
        const int n = gid;
        const int j = pos_j[n], i = pos_i[n], k = pos_k[n];
        const long off = (long)(2 * k) * HW + (long)j * WDIM + i;
        const float c0 = score[off], c1 = score[off + HW];
        const float m = fmaxf(c0, c1);
        const float lse = m + logf(expf(c0 - m) + expf(c1 - m));
        v = (lse - c1) * (1.0f / 16384.0f);
    } else if (gid < NP + NN) {
        // negative classification sample: CE vs class 0
        const int n = gid - NP;
        const int j = neg_j[n], i = neg_i[n], k = neg_k[n];
        const long off = (long)(2 * k) * HW + (long)j * WDIM + i;
        const float c0 = score[off], c1 = score[off + HW];
        const float m = fmaxf(c0, c1);
        const float lse = m + logf(expf(c0 - m) + expf(c1 - m));
        v = (lse - c0) * (1.0f / 16384.0f);
    } else if (gid < NP + NN + NV) {
        // vertical regression: SmoothL1 on 2 components, mean over Nv*2
        const int n = gid - NP - NN;
        const int j = vr_j[n], i = vr_i[n], k = vr_k[n];
        const long off = (long)(2 * k) * HW + (long)j * WDIM + i;
        const float p0 = vpred[off], p1 = vpred[off + HW];
        const float t0 = vr_tgt[2 * n], t1 = vr_tgt[2 * n + 1];
        v = (smooth_l1(p0 - t0) + smooth_l1(p1 - t1)) * (1.0f / 16384.0f);
    } else {
        // side refinement: SmoothL1 single component, mean over Ns
        const int n = gid - NP - NN - NV;
        const int j = sr_j[n], i = sr_i[n], k = sr_k[n];
        const long off = (long)k * HW + (long)j * WDIM + i;
        const float p = spred[off];
        v = smooth_l1(p - sr_tgt[n]) * (1.0f / 4096.0f);
    }

    // wave-64 tree reduction, then across the 4 waves via LDS (deterministic)
    #pragma unroll
    for (int s = 32; s > 0; s >>= 1) v += __shfl_down(v, s, 64);
    __shared__ float wsum[4];
    const int lane = threadIdx.x & 63;
    const int wid  = threadIdx.x >> 6;
    if (lane == 0) wsum[wid] = v;
    __syncthreads();
    if (threadIdx.x == 0)
        partial[blockIdx.x] = (wsum[0] + wsum[1]) + (wsum[2] + wsum[3]);
}

__global__ __launch_bounds__(128) void ctpn_final_kernel(
    const float* __restrict__ partial, float* __restrict__ out)
{
    float v = (threadIdx.x < NBLK) ? partial[threadIdx.x] : 0.0f;
    #pragma unroll
    for (int s = 32; s > 0; s >>= 1) v += __shfl_down(v, s, 64);
    __shared__ float wsum[2];
    const int lane = threadIdx.x & 63;
    const int wid  = threadIdx.x >> 6;
    if (lane == 0) wsum[wid] = v;
    __syncthreads();
    if (threadIdx.x == 0) out[0] = wsum[0] + wsum[1];
}

extern "C" void kernel_launch(void* const* d_in, const int* in_sizes, int n_in,
                              void* d_out, int out_size, void* d_ws, size_t ws_size,
                              hipStream_t stream) {
    const float* score = (const float*)d_in[0];
    const float* vpred = (const float*)d_in[1];
    const float* spred = (const float*)d_in[2];
    const int* pos_j = (const int*)d_in[3];
    const int* pos_i = (const int*)d_in[4];
    const int* pos_k = (const int*)d_in[5];
    const int* neg_j = (const int*)d_in[6];
    const int* neg_i = (const int*)d_in[7];
    const int* neg_k = (const int*)d_in[8];
    const int* vr_j  = (const int*)d_in[9];
    const int* vr_i  = (const int*)d_in[10];
    const int* vr_k  = (const int*)d_in[11];
    const float* vr_tgt = (const float*)d_in[12];
    const int* sr_j  = (const int*)d_in[13];
    const int* sr_i  = (const int*)d_in[14];
    const int* sr_k  = (const int*)d_in[15];
    const float* sr_tgt = (const float*)d_in[16];

    float* partial = (float*)d_ws;          // NBLK floats of scratch
    float* out = (float*)d_out;

    ctpn_partial_kernel<<<NBLK, 256, 0, stream>>>(
        score, vpred, spred,
        pos_j, pos_i, pos_k,
        neg_j, neg_i, neg_k,
        vr_j, vr_i, vr_k, vr_tgt,
        sr_j, sr_i, sr_k, sr_tgt,
        partial);
    ctpn_final_kernel<<<1, 128, 0, stream>>>(partial, out);
}